// Round 10
// baseline (105.250 us; speedup 1.0000x reference)
//
#include <hip/hip_runtime.h>
#include <hip/hip_bf16.h>
#include <stdint.h>

#define BATCH 8
#define TSEQ 2048
#define DM 1024
#define NQKV 192

typedef short bf16x8 __attribute__((ext_vector_type(8)));
typedef short short4v __attribute__((ext_vector_type(4)));
typedef float f32x4 __attribute__((ext_vector_type(4)));

static __device__ __forceinline__ short f2bf(float f) {
    union { float f; uint32_t u; } v; v.f = f;
    uint32_t u = v.u;
    uint32_t r = (u + 0x7FFFu + ((u >> 16) & 1u)) >> 16;
    return (short)r;
}

static __device__ __forceinline__ f32x4 mfma16(bf16x8 a, bf16x8 b, f32x4 c) {
    return __builtin_amdgcn_mfma_f32_16x16x32_bf16(a, b, c, 0, 0, 0);
}

// Kernel 0: wt2[kchunk=0..127][n=0..191][8]. grid 128 x 192 threads.
__global__ __launch_bounds__(192) void prep_wt(const float* __restrict__ Wq,
                                               const float* __restrict__ Wk,
                                               const float* __restrict__ Wv,
                                               short* __restrict__ wt2) {
    int kc = blockIdx.x;
    int n = threadIdx.x;
    const float* src = (n < 64) ? Wq : (n < 128) ? Wk : Wv;
    int nn = n & 63;
    bf16x8 v;
    #pragma unroll
    for (int e = 0; e < 8; ++e)
        v[e] = f2bf(src[(kc * 8 + e) * 64 + nn]);
    *(bf16x8*)(wt2 + ((size_t)kc * 192 + n) * 8) = v;
}

// Kernel 1: QKV GEMM (R7 configuration — best measured).
__global__ __launch_bounds__(256, 2) void qkv_gemm(const float* __restrict__ x,
                                                   const short* __restrict__ wt2,
                                                   short* __restrict__ qo,
                                                   short* __restrict__ kq,
                                                   short* __restrict__ vq) {
    __shared__ short Ab[2][32 * 32];   // 2 x 2 KB bf16
    __shared__ short Cs[32][192];      // 12 KB epilogue staging
    int tid = threadIdx.x;
    int l = tid & 63, w = tid >> 6;
    int col = l & 15, g = l >> 4;
    int row0 = blockIdx.x * 32;

    int arow = tid >> 3, ap = tid & 7;
    const float* gA = x + (size_t)(row0 + arow) * DM + ap * 4;
    int awdst = arow * 32 + (((ap >> 1) ^ ((arow >> 1) & 3)) * 8) + (ap & 1) * 4;

    f32x4 acc[2][3];
    #pragma unroll
    for (int mf = 0; mf < 2; ++mf)
        #pragma unroll
        for (int nf = 0; nf < 3; ++nf) acc[mf][nf] = (f32x4){0.f, 0.f, 0.f, 0.f};

    float4 r0 = *(const float4*)(gA);
    float4 rcur = *(const float4*)(gA + 32);
    {
        short4v s = {f2bf(r0.x), f2bf(r0.y), f2bf(r0.z), f2bf(r0.w)};
        *(short4v*)&Ab[0][awdst] = s;
    }
    const short* bpw = wt2 + ((size_t)g * 192 + w * 48 + col) * 8;
    bf16x8 bcur[3], bnxt[3];
    #pragma unroll
    for (int nf = 0; nf < 3; ++nf)
        bcur[nf] = *(const bf16x8*)(bpw + (size_t)nf * 16 * 8);
    __syncthreads();

    int afr0, afr1;
    {
        int r0_ = col, r1_ = 16 + col;
        afr0 = r0_ * 32 + ((g ^ ((r0_ >> 1) & 3)) * 8);
        afr1 = r1_ * 32 + ((g ^ ((r1_ >> 1) & 3)) * 8);
    }

    for (int t = 0; t < 32; ++t) {
        float4 rn;
        if (t + 2 < 32) rn = *(const float4*)(gA + (t + 2) * 32);
        if (t + 1 < 32) {
            #pragma unroll
            for (int nf = 0; nf < 3; ++nf)
                bnxt[nf] = *(const bf16x8*)(bpw + ((size_t)(t + 1) * 4 * 192 + nf * 16) * 8);
            short4v s = {f2bf(rcur.x), f2bf(rcur.y), f2bf(rcur.z), f2bf(rcur.w)};
            *(short4v*)&Ab[(t + 1) & 1][awdst] = s;
        }
        bf16x8 a0 = *(const bf16x8*)&Ab[t & 1][afr0];
        bf16x8 a1 = *(const bf16x8*)&Ab[t & 1][afr1];
        #pragma unroll
        for (int nf = 0; nf < 3; ++nf) {
            acc[0][nf] = mfma16(a0, bcur[nf], acc[0][nf]);
            acc[1][nf] = mfma16(a1, bcur[nf], acc[1][nf]);
        }
        __syncthreads();
        rcur = rn;
        #pragma unroll
        for (int nf = 0; nf < 3; ++nf) bcur[nf] = bnxt[nf];
    }

    #pragma unroll
    for (int mf = 0; mf < 2; ++mf)
        #pragma unroll
        for (int nf = 0; nf < 3; ++nf) {
            int c = w * 48 + nf * 16 + col;
            #pragma unroll
            for (int j = 0; j < 4; ++j) {
                float sv = acc[mf][nf][j];
                if (c < 64) sv *= 0.03125f;
                Cs[mf * 16 + g * 4 + j][c] = f2bf(sv);
            }
        }
    __syncthreads();
    int b_ = row0 >> 11;
    int t0 = row0 & 2047;
    {
        int r = tid >> 3, c0 = (tid & 7) * 8;
        bf16x8 vv = *(const bf16x8*)&Cs[r][c0];
        *(bf16x8*)(qo + ((size_t)(b_ * TSEQ + t0 + r)) * 64 + c0) = vv;
    }
    {
        int chunk = tid >> 5, tl = tid & 31;
        bf16x8 vv = *(const bf16x8*)&Cs[tl][64 + chunk * 8];
        *(bf16x8*)(kq + ((size_t)(b_ * 8 + chunk) * TSEQ + t0 + tl) * 8) = vv;
    }
    {
        int tc = tid >> 6, d = tid & 63;
        bf16x8 vv;
        #pragma unroll
        for (int e = 0; e < 8; ++e) vv[e] = Cs[tc * 8 + e][128 + d];
        *(bf16x8*)(vq + (((size_t)b_ * 256 + (t0 >> 3) + tc) * 64 + d) * 8) = vv;
    }
}

// Kernel 2: causal flash attention (R6/R7 configuration).
__global__ __launch_bounds__(256) void attn(const short* __restrict__ qm,
                                            const short* __restrict__ kq,
                                            const short* __restrict__ vq,
                                            float* __restrict__ out) {
    __shared__ short Pb[4][16 * 64];
    __shared__ float Om[2][16][64];
    __shared__ float Ps[2][16];
    int tid = threadIdx.x;
    int l = tid & 63, w = tid >> 6;
    int col = l & 15, g = l >> 4;

    int Bk = blockIdx.x;
    int bb = Bk & 7;
    int jj = Bk >> 3;
    bool high = (jj < 32);
    int qt, kt0, kt1;
    if (high) {
        int hp = 62 - 2 * jj + (w >> 1);
        qt = 64 + hp;
        int nt = (qt >> 2) + 1;
        int nh = nt >> 1;
        kt0 = (w & 1) ? nh : 0;
        kt1 = (w & 1) ? nt : nh;
    } else {
        int i = 47 - jj;
        qt = 4 * i + w;
        kt0 = 0;
        kt1 = (qt >> 2) + 1;
    }
    int q0 = qt * 16;
    int lastkt = qt >> 2;

    const short* qrow = qm + (size_t)(bb * TSEQ + q0 + col) * 64 + g * 8;
    bf16x8 qa0 = *(const bf16x8*)(qrow);
    bf16x8 qa1 = *(const bf16x8*)(qrow + 32);

    const short* kb_ = kq + (size_t)(bb * 8 + g) * TSEQ * 8;
    const short* kb4 = kq + (size_t)(bb * 8 + 4 + g) * TSEQ * 8;
    const short* vb_ = vq + ((size_t)bb * 256 + g) * 64 * 8;

    float psum[4] = {0.f, 0.f, 0.f, 0.f};
    f32x4 o[4];
    #pragma unroll
    for (int df = 0; df < 4; ++df) o[df] = (f32x4){0.f, 0.f, 0.f, 0.f};

    short* Pw = &Pb[w][0];

    bf16x8 kcur[8], knxt[8];
    {
        int key0 = kt0 * 64 + col;
        #pragma unroll
        for (int kf = 0; kf < 4; ++kf) {
            kcur[kf * 2]     = *(const bf16x8*)(kb_ + (size_t)(key0 + kf * 16) * 8);
            kcur[kf * 2 + 1] = *(const bf16x8*)(kb4 + (size_t)(key0 + kf * 16) * 8);
        }
    }

    for (int kt = kt0; kt < kt1; ++kt) {
        int k0 = kt * 64;
        f32x4 s[4];
        #pragma unroll
        for (int kf = 0; kf < 4; ++kf) {
            f32x4 a = (f32x4){0.f, 0.f, 0.f, 0.f};
            a = mfma16(qa0, kcur[kf * 2], a);
            a = mfma16(qa1, kcur[kf * 2 + 1], a);
            s[kf] = a;
        }
        bf16x8 vfr[8];
        const short* vt0 = vb_ + (size_t)(k0 >> 3) * 64 * 8;
        #pragma unroll
        for (int df = 0; df < 4; ++df) {
            int d = df * 16 + col;
            vfr[df * 2]     = *(const bf16x8*)(vt0 + (size_t)d * 8);
            vfr[df * 2 + 1] = *(const bf16x8*)(vt0 + (size_t)(256 + d) * 8);
        }
        if (kt + 1 < kt1) {
            int key0 = (kt + 1) * 64 + col;
            #pragma unroll
            for (int kf = 0; kf < 4; ++kf) {
                knxt[kf * 2]     = *(const bf16x8*)(kb_ + (size_t)(key0 + kf * 16) * 8);
                knxt[kf * 2 + 1] = *(const bf16x8*)(kb4 + (size_t)(key0 + kf * 16) * 8);
            }
        }
        if (kt == lastkt) {
            #pragma unroll
            for (int kf = 0; kf < 4; ++kf) {
                int key = k0 + kf * 16 + col;
                #pragma unroll
                for (int j = 0; j < 4; ++j)
                    if (key > q0 + g * 4 + j) s[kf][j] = -1e30f;
            }
        }
        #pragma unroll
        for (int kf = 0; kf < 4; ++kf)
            #pragma unroll
            for (int j = 0; j < 4; ++j) {
                float pv = __expf(s[kf][j]);
                psum[j] += pv;
                int rr = g * 4 + j;
                int c = kf * 16 + col;
                Pw[rr * 64 + ((((c >> 3) ^ (rr & 7)) << 3) | (c & 7))] = f2bf(pv);
            }
        bf16x8 pa0 = *(const bf16x8*)(Pw + col * 64 + ((g ^ (col & 7)) << 3));
        bf16x8 pa1 = *(const bf16x8*)(Pw + col * 64 + (((4 + g) ^ (col & 7)) << 3));
        #pragma unroll
        for (int df = 0; df < 4; ++df) {
            o[df] = mfma16(pa0, vfr[df * 2], o[df]);
            o[df] = mfma16(pa1, vfr[df * 2 + 1], o[df]);
        }
        #pragma unroll
        for (int i2 = 0; i2 < 8; ++i2) kcur[i2] = knxt[i2];
    }

    #pragma unroll
    for (int off = 1; off <= 8; off <<= 1)
        #pragma unroll
        for (int j = 0; j < 4; ++j)
            psum[j] += __shfl_xor(psum[j], off);

    if (high) {
        int pr = w >> 1;
        if (w & 1) {
            #pragma unroll
            for (int df = 0; df < 4; ++df)
                #pragma unroll
                for (int j = 0; j < 4; ++j)
                    Om[pr][g * 4 + j][df * 16 + col] = o[df][j];
            if (col == 0)
                #pragma unroll
                for (int j = 0; j < 4; ++j) Ps[pr][g * 4 + j] = psum[j];
        }
        __syncthreads();
        if (!(w & 1)) {
            float inv[4];
            #pragma unroll
            for (int j = 0; j < 4; ++j) inv[j] = 1.f / (psum[j] + Ps[pr][g * 4 + j]);
            #pragma unroll
            for (int df = 0; df < 4; ++df)
                #pragma unroll
                for (int j = 0; j < 4; ++j) {
                    float vv = (o[df][j] + Om[pr][g * 4 + j][df * 16 + col]) * inv[j];
                    out[(size_t)(bb * TSEQ + q0 + g * 4 + j) * 64 + df * 16 + col] = vv;
                }
        }
    } else {
        #pragma unroll
        for (int df = 0; df < 4; ++df)
            #pragma unroll
            for (int j = 0; j < 4; ++j)
                out[(size_t)(bb * TSEQ + q0 + g * 4 + j) * 64 + df * 16 + col] = o[df][j] / psum[j];
    }
}

extern "C" void kernel_launch(void* const* d_in, const int* in_sizes, int n_in,
                              void* d_out, int out_size, void* d_ws, size_t ws_size,
                              hipStream_t stream) {
    const float* x  = (const float*)d_in[0];
    const float* Wq = (const float*)d_in[1];
    const float* Wk = (const float*)d_in[2];
    const float* Wv = (const float*)d_in[3];
    float* out = (float*)d_out;

    char* ws = (char*)d_ws;
    short* wt2 = (short*)(ws);                        // 384 KB
    short* qb  = (short*)(ws + 0x60000);              // 2 MB
    short* kqb = (short*)(ws + 0x60000 + 0x200000);   // 2 MB
    short* vqb = (short*)(ws + 0x60000 + 0x400000);   // 2 MB

    prep_wt<<<128, 192, 0, stream>>>(Wq, Wk, Wv, wt2);
    // MEASUREMENT: qkv launched 5x (idempotent). T - 44.98 = 4 * t_qkv.
    for (int rep = 0; rep < 5; ++rep)
        qkv_gemm<<<512, 256, 0, stream>>>(x, wt2, qb, kqb, vqb);
    attn<<<384, 256, 0, stream>>>(qb, kqb, vqb, out);
}

// Round 11
// 48.812 us; speedup vs baseline: 2.1563x; 2.1563x over previous
//
#include <hip/hip_runtime.h>
#include <hip/hip_bf16.h>
#include <stdint.h>

#define BATCH 8
#define TSEQ 2048
#define DM 1024
#define NQKV 192

typedef short bf16x8 __attribute__((ext_vector_type(8)));
typedef short short4v __attribute__((ext_vector_type(4)));
typedef float f32x4 __attribute__((ext_vector_type(4)));

#define AS1 __attribute__((address_space(1)))
#define AS3 __attribute__((address_space(3)))

static __device__ __forceinline__ short f2bf(float f) {
    union { float f; uint32_t u; } v; v.f = f;
    uint32_t u = v.u;
    uint32_t r = (u + 0x7FFFu + ((u >> 16) & 1u)) >> 16;
    return (short)r;
}

static __device__ __forceinline__ f32x4 mfma16(bf16x8 a, bf16x8 b, f32x4 c) {
    return __builtin_amdgcn_mfma_f32_16x16x32_bf16(a, b, c, 0, 0, 0);
}

static __device__ __forceinline__ void gl16(const void* g, void* l) {
    __builtin_amdgcn_global_load_lds((const AS1 void*)g, (AS3 void*)l, 16, 0, 0);
}

// Kernel 0: wt2[kchunk=0..127][n=0..191][8]. grid 128 x 192 threads.
__global__ __launch_bounds__(192) void prep_wt(const float* __restrict__ Wq,
                                               const float* __restrict__ Wk,
                                               const float* __restrict__ Wv,
                                               short* __restrict__ wt2) {
    int kc = blockIdx.x;
    int n = threadIdx.x;
    const float* src = (n < 64) ? Wq : (n < 128) ? Wk : Wv;
    int nn = n & 63;
    bf16x8 v;
    #pragma unroll
    for (int e = 0; e < 8; ++e)
        v[e] = f2bf(src[(kc * 8 + e) * 64 + nn]);
    *(bf16x8*)(wt2 + ((size_t)kc * 192 + n) * 8) = v;
}

// Kernel 1: QKV GEMM (R7 configuration, measured 15.1 us).
__global__ __launch_bounds__(256, 2) void qkv_gemm(const float* __restrict__ x,
                                                   const short* __restrict__ wt2,
                                                   short* __restrict__ qo,
                                                   short* __restrict__ kq,
                                                   short* __restrict__ vq) {
    __shared__ short Ab[2][32 * 32];
    __shared__ short Cs[32][192];
    int tid = threadIdx.x;
    int l = tid & 63, w = tid >> 6;
    int col = l & 15, g = l >> 4;
    int row0 = blockIdx.x * 32;

    int arow = tid >> 3, ap = tid & 7;
    const float* gA = x + (size_t)(row0 + arow) * DM + ap * 4;
    int awdst = arow * 32 + (((ap >> 1) ^ ((arow >> 1) & 3)) * 8) + (ap & 1) * 4;

    f32x4 acc[2][3];
    #pragma unroll
    for (int mf = 0; mf < 2; ++mf)
        #pragma unroll
        for (int nf = 0; nf < 3; ++nf) acc[mf][nf] = (f32x4){0.f, 0.f, 0.f, 0.f};

    float4 r0 = *(const float4*)(gA);
    float4 rcur = *(const float4*)(gA + 32);
    {
        short4v s = {f2bf(r0.x), f2bf(r0.y), f2bf(r0.z), f2bf(r0.w)};
        *(short4v*)&Ab[0][awdst] = s;
    }
    const short* bpw = wt2 + ((size_t)g * 192 + w * 48 + col) * 8;
    bf16x8 bcur[3], bnxt[3];
    #pragma unroll
    for (int nf = 0; nf < 3; ++nf)
        bcur[nf] = *(const bf16x8*)(bpw + (size_t)nf * 16 * 8);
    __syncthreads();

    int afr0, afr1;
    {
        int r0_ = col, r1_ = 16 + col;
        afr0 = r0_ * 32 + ((g ^ ((r0_ >> 1) & 3)) * 8);
        afr1 = r1_ * 32 + ((g ^ ((r1_ >> 1) & 3)) * 8);
    }

    for (int t = 0; t < 32; ++t) {
        float4 rn;
        if (t + 2 < 32) rn = *(const float4*)(gA + (t + 2) * 32);
        if (t + 1 < 32) {
            #pragma unroll
            for (int nf = 0; nf < 3; ++nf)
                bnxt[nf] = *(const bf16x8*)(bpw + ((size_t)(t + 1) * 4 * 192 + nf * 16) * 8);
            short4v s = {f2bf(rcur.x), f2bf(rcur.y), f2bf(rcur.z), f2bf(rcur.w)};
            *(short4v*)&Ab[(t + 1) & 1][awdst] = s;
        }
        bf16x8 a0 = *(const bf16x8*)&Ab[t & 1][afr0];
        bf16x8 a1 = *(const bf16x8*)&Ab[t & 1][afr1];
        #pragma unroll
        for (int nf = 0; nf < 3; ++nf) {
            acc[0][nf] = mfma16(a0, bcur[nf], acc[0][nf]);
            acc[1][nf] = mfma16(a1, bcur[nf], acc[1][nf]);
        }
        __syncthreads();
        rcur = rn;
        #pragma unroll
        for (int nf = 0; nf < 3; ++nf) bcur[nf] = bnxt[nf];
    }

    #pragma unroll
    for (int mf = 0; mf < 2; ++mf)
        #pragma unroll
        for (int nf = 0; nf < 3; ++nf) {
            int c = w * 48 + nf * 16 + col;
            #pragma unroll
            for (int j = 0; j < 4; ++j) {
                float sv = acc[mf][nf][j];
                if (c < 64) sv *= 0.03125f;
                Cs[mf * 16 + g * 4 + j][c] = f2bf(sv);
            }
        }
    __syncthreads();
    int b_ = row0 >> 11;
    int t0 = row0 & 2047;
    {
        int r = tid >> 3, c0 = (tid & 7) * 8;
        bf16x8 vv = *(const bf16x8*)&Cs[r][c0];
        *(bf16x8*)(qo + ((size_t)(b_ * TSEQ + t0 + r)) * 64 + c0) = vv;
    }
    {
        int chunk = tid >> 5, tl = tid & 31;
        bf16x8 vv = *(const bf16x8*)&Cs[tl][64 + chunk * 8];
        *(bf16x8*)(kq + ((size_t)(b_ * 8 + chunk) * TSEQ + t0 + tl) * 8) = vv;
    }
    {
        int tc = tid >> 6, d = tid & 63;
        bf16x8 vv;
        #pragma unroll
        for (int e = 0; e < 8; ++e) vv[e] = Cs[tc * 8 + e][128 + d];
        *(bf16x8*)(vq + (((size_t)b_ * 256 + (t0 >> 3) + tc) * 64 + d) * 8) = vv;
    }
}

// Kernel 2: causal flash attention, block-shared LDS K/V staging.
// grid 384 x 256 (4 waves x 16 q-rows = 64 rows/block, shared key stream).
// qg<16: one block (tiles 0..qg). qg>=16: two key-partition blocks.
// K LDS: [dchunk 0..7][key 0..63] 16B units; V LDS: [kchunk 0..7][d 0..63].
// Staged via global_load_lds, contiguous 1KB/instr sources, 3-buf, vmcnt(4).
__global__ __launch_bounds__(256, 2) void attn(const short* __restrict__ qm,
                                               const short* __restrict__ kq,
                                               const short* __restrict__ vq,
                                               float* __restrict__ out,
                                               float* __restrict__ ob1,
                                               float* __restrict__ pb0,
                                               float* __restrict__ pb1) {
    __shared__ short Kb[3][4096];   // 3 x 8 KB
    __shared__ short Vb[3][4096];   // 3 x 8 KB
    __shared__ short Pb[4][1024];   // 8 KB
    int tid = threadIdx.x;
    int l = tid & 63, w = tid >> 6;
    int col = l & 15, g = l >> 4;

    int Bk = blockIdx.x;
    int bb = Bk & 7;
    int id = Bk >> 3;                 // 0..47
    int qg, kt0, kt1;
    if (id < 16) {
        qg = id; kt0 = 0; kt1 = qg + 1;
    } else {
        int sp = id - 16;             // 0..31
        qg = 16 + (sp >> 1);
        int nt = qg + 1, h0 = (nt + 1) >> 1;
        if (sp & 1) { kt0 = h0; kt1 = nt; } else { kt0 = 0; kt1 = h0; }
    }
    int q0w = qg * 64 + w * 16;

    // Q fragments
    const short* qrow = qm + (size_t)(bb * TSEQ + q0w + col) * 64 + g * 8;
    bf16x8 qa0 = *(const bf16x8*)(qrow);
    bf16x8 qa1 = *(const bf16x8*)(qrow + 32);

    // staging source bases (thread -> chunk tid>>6 == w, elem tid&63)
    int lane6 = tid & 63;
    const short* kS0 = kq + (((size_t)bb * 8 + w) * TSEQ + lane6) * 8;
    const short* kS1 = kq + (((size_t)bb * 8 + w + 4) * TSEQ + lane6) * 8;
    const short* vS0 = vq + (((size_t)bb * 256 + w) * 64 + lane6) * 8;
    const short* vS1 = vq + (((size_t)bb * 256 + w + 4) * 64 + lane6) * 8;

    float psum[4] = {0.f, 0.f, 0.f, 0.f};
    f32x4 o[4];
    #pragma unroll
    for (int df = 0; df < 4; ++df) o[df] = (f32x4){0.f, 0.f, 0.f, 0.f};

    short* Pw = &Pb[w][0];
    int nloc = kt1 - kt0;

    #define STAGE(bi, kt)  do { \
        gl16(kS0 + (size_t)(kt) * 512,  &Kb[bi][tid * 8]); \
        gl16(kS1 + (size_t)(kt) * 512,  &Kb[bi][(tid + 256) * 8]); \
        gl16(vS0 + (size_t)(kt) * 4096, &Vb[bi][tid * 8]); \
        gl16(vS1 + (size_t)(kt) * 4096, &Vb[bi][(tid + 256) * 8]); \
    } while (0)

    STAGE(0, kt0);
    if (nloc > 1) STAGE(1, kt0 + 1);

    for (int i = 0; i < nloc; ++i) {
        int kt = kt0 + i;
        if (i + 1 < nloc) {
            asm volatile("s_waitcnt vmcnt(4)" ::: "memory");
        } else {
            asm volatile("s_waitcnt vmcnt(0)" ::: "memory");
        }
        __builtin_amdgcn_s_barrier();
        if (i + 2 < nloc) {
            int bi = (i + 2) % 3;
            STAGE(bi, kt + 2);
        }
        int cb = i % 3;

        // S = Q K^T from LDS
        f32x4 s[4];
        #pragma unroll
        for (int kf = 0; kf < 4; ++kf) {
            bf16x8 kb0 = *(const bf16x8*)&Kb[cb][(g * 64 + kf * 16 + col) * 8];
            bf16x8 kb1 = *(const bf16x8*)&Kb[cb][((4 + g) * 64 + kf * 16 + col) * 8];
            f32x4 a = (f32x4){0.f, 0.f, 0.f, 0.f};
            a = mfma16(qa0, kb0, a);
            a = mfma16(qa1, kb1, a);
            s[kf] = a;
        }
        // mask (global diagonal tile only)
        if (kt == qg) {
            #pragma unroll
            for (int kf = 0; kf < 4; ++kf) {
                int key = kt * 64 + kf * 16 + col;
                #pragma unroll
                for (int j = 0; j < 4; ++j)
                    if (key > q0w + g * 4 + j) s[kf][j] = -1e30f;
            }
        }
        // p = exp(s), partial sums, pack transposed into per-wave LDS
        #pragma unroll
        for (int kf = 0; kf < 4; ++kf)
            #pragma unroll
            for (int j = 0; j < 4; ++j) {
                float pv = __expf(s[kf][j]);
                psum[j] += pv;
                int rr = g * 4 + j;
                int c = kf * 16 + col;
                Pw[rr * 64 + ((((c >> 3) ^ (rr & 7)) << 3) | (c & 7))] = f2bf(pv);
            }
        bf16x8 pa0 = *(const bf16x8*)(Pw + col * 64 + ((g ^ (col & 7)) << 3));
        bf16x8 pa1 = *(const bf16x8*)(Pw + col * 64 + (((4 + g) ^ (col & 7)) << 3));
        // O += P V from LDS
        #pragma unroll
        for (int df = 0; df < 4; ++df) {
            bf16x8 vb0 = *(const bf16x8*)&Vb[cb][(g * 64 + df * 16 + col) * 8];
            bf16x8 vb1 = *(const bf16x8*)&Vb[cb][((4 + g) * 64 + df * 16 + col) * 8];
            o[df] = mfma16(pa0, vb0, o[df]);
            o[df] = mfma16(pa1, vb1, o[df]);
        }
    }
    #undef STAGE

    // row-sum reduce across the 16 col lanes
    #pragma unroll
    for (int off = 1; off <= 8; off <<= 1)
        #pragma unroll
        for (int j = 0; j < 4; ++j)
            psum[j] += __shfl_xor(psum[j], off);

    if (kt0 == 0) {
        // part0 (or whole): raw o -> out, psum -> pb0
        #pragma unroll
        for (int df = 0; df < 4; ++df)
            #pragma unroll
            for (int j = 0; j < 4; ++j)
                out[((size_t)bb * TSEQ + q0w + g * 4 + j) * 64 + df * 16 + col] = o[df][j];
        if (col == 0)
            #pragma unroll
            for (int j = 0; j < 4; ++j)
                pb0[bb * TSEQ + q0w + g * 4 + j] = psum[j];
    } else {
        // part1 (rows >= 1024 only): o -> ob1, psum -> pb1
        #pragma unroll
        for (int df = 0; df < 4; ++df)
            #pragma unroll
            for (int j = 0; j < 4; ++j)
                ob1[((size_t)bb * 1024 + (q0w - 1024) + g * 4 + j) * 64 + df * 16 + col] = o[df][j];
        if (col == 0)
            #pragma unroll
            for (int j = 0; j < 4; ++j)
                pb1[bb * TSEQ + q0w + g * 4 + j] = psum[j];
    }
}

// Kernel 3: normalize. out[row][:] = (out + ob1?)/(pb0 + pb1?). grid 1024 x 256.
__global__ __launch_bounds__(256) void norm_out(float* __restrict__ out,
                                                const float* __restrict__ ob1,
                                                const float* __restrict__ pb0,
                                                const float* __restrict__ pb1) {
    int idx = blockIdx.x * 256 + threadIdx.x;   // float4 index
    int e0 = idx * 4;
    int row = e0 >> 6;
    int t = row & 2047, b = row >> 11;
    float4 v = ((const float4*)out)[idx];
    float p = pb0[row];
    if (t >= 1024) {
        p += pb1[row];
        float4 o1 = ((const float4*)ob1)[((size_t)b * 1024 + (t - 1024)) * 16 + ((e0 & 63) >> 2)];
        v.x += o1.x; v.y += o1.y; v.z += o1.z; v.w += o1.w;
    }
    float inv = 1.f / p;
    v.x *= inv; v.y *= inv; v.z *= inv; v.w *= inv;
    ((float4*)out)[idx] = v;
}

extern "C" void kernel_launch(void* const* d_in, const int* in_sizes, int n_in,
                              void* d_out, int out_size, void* d_ws, size_t ws_size,
                              hipStream_t stream) {
    const float* x  = (const float*)d_in[0];
    const float* Wq = (const float*)d_in[1];
    const float* Wk = (const float*)d_in[2];
    const float* Wv = (const float*)d_in[3];
    float* out = (float*)d_out;

    char* ws = (char*)d_ws;
    short* wt2 = (short*)(ws);                        // 384 KB
    short* qb  = (short*)(ws + 0x60000);              // 2 MB
    short* kqb = (short*)(ws + 0x260000);             // 2 MB
    short* vqb = (short*)(ws + 0x460000);             // 2 MB
    float* pb0 = (float*)(ws + 0x660000);             // 64 KB
    float* pb1 = (float*)(ws + 0x670000);             // 64 KB
    float* ob1 = (float*)(ws + 0x680000);             // 2 MB (rows >= 1024 partials)

    prep_wt<<<128, 192, 0, stream>>>(Wq, Wk, Wv, wt2);
    qkv_gemm<<<512, 256, 0, stream>>>(x, wt2, qb, kqb, vqb);
    attn<<<384, 256, 0, stream>>>(qb, kqb, vqb, out, ob1, pb0, pb1);
    norm_out<<<1024, 256, 0, stream>>>(out, ob1, pb0, pb1);
}

// Round 12
// 47.517 us; speedup vs baseline: 2.2150x; 1.0272x over previous
//
#include <hip/hip_runtime.h>
#include <hip/hip_bf16.h>
#include <stdint.h>

#define BATCH 8
#define TSEQ 2048
#define DM 1024
#define NQKV 192

typedef short bf16x8 __attribute__((ext_vector_type(8)));
typedef short short4v __attribute__((ext_vector_type(4)));
typedef float f32x4 __attribute__((ext_vector_type(4)));

static __device__ __forceinline__ short f2bf(float f) {
    union { float f; uint32_t u; } v; v.f = f;
    uint32_t u = v.u;
    uint32_t r = (u + 0x7FFFu + ((u >> 16) & 1u)) >> 16;
    return (short)r;
}

static __device__ __forceinline__ f32x4 mfma16(bf16x8 a, bf16x8 b, f32x4 c) {
    return __builtin_amdgcn_mfma_f32_16x16x32_bf16(a, b, c, 0, 0, 0);
}

// Kernel 0: wt2[kchunk=0..127][n=0..191][8]. grid 128 x 192 threads.
__global__ __launch_bounds__(192) void prep_wt(const float* __restrict__ Wq,
                                               const float* __restrict__ Wk,
                                               const float* __restrict__ Wv,
                                               short* __restrict__ wt2) {
    int kc = blockIdx.x;
    int n = threadIdx.x;
    const float* src = (n < 64) ? Wq : (n < 128) ? Wk : Wv;
    int nn = n & 63;
    bf16x8 v;
    #pragma unroll
    for (int e = 0; e < 8; ++e)
        v[e] = f2bf(src[(kc * 8 + e) * 64 + nn]);
    *(bf16x8*)(wt2 + ((size_t)kc * 192 + n) * 8) = v;
}

// Kernel 1: QKV GEMM (R7 configuration, measured 15.1 us). Unchanged.
__global__ __launch_bounds__(256, 2) void qkv_gemm(const float* __restrict__ x,
                                                   const short* __restrict__ wt2,
                                                   short* __restrict__ qo,
                                                   short* __restrict__ kq,
                                                   short* __restrict__ vq) {
    __shared__ short Ab[2][32 * 32];
    __shared__ short Cs[32][192];
    int tid = threadIdx.x;
    int l = tid & 63, w = tid >> 6;
    int col = l & 15, g = l >> 4;
    int row0 = blockIdx.x * 32;

    int arow = tid >> 3, ap = tid & 7;
    const float* gA = x + (size_t)(row0 + arow) * DM + ap * 4;
    int awdst = arow * 32 + (((ap >> 1) ^ ((arow >> 1) & 3)) * 8) + (ap & 1) * 4;

    f32x4 acc[2][3];
    #pragma unroll
    for (int mf = 0; mf < 2; ++mf)
        #pragma unroll
        for (int nf = 0; nf < 3; ++nf) acc[mf][nf] = (f32x4){0.f, 0.f, 0.f, 0.f};

    float4 r0 = *(const float4*)(gA);
    float4 rcur = *(const float4*)(gA + 32);
    {
        short4v s = {f2bf(r0.x), f2bf(r0.y), f2bf(r0.z), f2bf(r0.w)};
        *(short4v*)&Ab[0][awdst] = s;
    }
    const short* bpw = wt2 + ((size_t)g * 192 + w * 48 + col) * 8;
    bf16x8 bcur[3], bnxt[3];
    #pragma unroll
    for (int nf = 0; nf < 3; ++nf)
        bcur[nf] = *(const bf16x8*)(bpw + (size_t)nf * 16 * 8);
    __syncthreads();

    int afr0, afr1;
    {
        int r0_ = col, r1_ = 16 + col;
        afr0 = r0_ * 32 + ((g ^ ((r0_ >> 1) & 3)) * 8);
        afr1 = r1_ * 32 + ((g ^ ((r1_ >> 1) & 3)) * 8);
    }

    for (int t = 0; t < 32; ++t) {
        float4 rn;
        if (t + 2 < 32) rn = *(const float4*)(gA + (t + 2) * 32);
        if (t + 1 < 32) {
            #pragma unroll
            for (int nf = 0; nf < 3; ++nf)
                bnxt[nf] = *(const bf16x8*)(bpw + ((size_t)(t + 1) * 4 * 192 + nf * 16) * 8);
            short4v s = {f2bf(rcur.x), f2bf(rcur.y), f2bf(rcur.z), f2bf(rcur.w)};
            *(short4v*)&Ab[(t + 1) & 1][awdst] = s;
        }
        bf16x8 a0 = *(const bf16x8*)&Ab[t & 1][afr0];
        bf16x8 a1 = *(const bf16x8*)&Ab[t & 1][afr1];
        #pragma unroll
        for (int nf = 0; nf < 3; ++nf) {
            acc[0][nf] = mfma16(a0, bcur[nf], acc[0][nf]);
            acc[1][nf] = mfma16(a1, bcur[nf], acc[1][nf]);
        }
        __syncthreads();
        rcur = rn;
        #pragma unroll
        for (int nf = 0; nf < 3; ++nf) bcur[nf] = bnxt[nf];
    }

    #pragma unroll
    for (int mf = 0; mf < 2; ++mf)
        #pragma unroll
        for (int nf = 0; nf < 3; ++nf) {
            int c = w * 48 + nf * 16 + col;
            #pragma unroll
            for (int j = 0; j < 4; ++j) {
                float sv = acc[mf][nf][j];
                if (c < 64) sv *= 0.03125f;
                Cs[mf * 16 + g * 4 + j][c] = f2bf(sv);
            }
        }
    __syncthreads();
    int b_ = row0 >> 11;
    int t0 = row0 & 2047;
    {
        int r = tid >> 3, c0 = (tid & 7) * 8;
        bf16x8 vv = *(const bf16x8*)&Cs[r][c0];
        *(bf16x8*)(qo + ((size_t)(b_ * TSEQ + t0 + r)) * 64 + c0) = vv;
    }
    {
        int chunk = tid >> 5, tl = tid & 31;
        bf16x8 vv = *(const bf16x8*)&Cs[tl][64 + chunk * 8];
        *(bf16x8*)(kq + ((size_t)(b_ * 8 + chunk) * TSEQ + t0 + tl) * 8) = vv;
    }
    {
        int tc = tid >> 6, d = tid & 63;
        bf16x8 vv;
        #pragma unroll
        for (int e = 0; e < 8; ++e) vv[e] = Cs[tc * 8 + e][128 + d];
        *(bf16x8*)(vq + (((size_t)b_ * 256 + (t0 >> 3) + tc) * 64 + d) * 8) = vv;
    }
}

// Kernel 2: causal flash attention, uniform fine-grained key-split.
// Wave = (b, 16-row q-tile qt, chunk ci of <=4 key-tiles). 4608 waves total,
// grid 1152 x 256 (4 independent waves/block, no barriers). Each wave writes
// raw partial O (fp32 16x64) + psum to slot gid. chunks(qt) = (qt>>4)+1.
__global__ __launch_bounds__(256) void attn(const short* __restrict__ qm,
                                            const short* __restrict__ kq,
                                            const short* __restrict__ vq,
                                            float* __restrict__ pob,
                                            float* __restrict__ pps) {
    __shared__ short Pb[4][1024];
    int tid = threadIdx.x;
    int l = tid & 63, w = tid >> 6;
    int col = l & 15, g = l >> 4;

    int gid = blockIdx.x * 4 + w;
    int b = gid / 576;
    int rem = gid - b * 576;
    // invert prefix: block h occupies [8h(h+1), 8(h+1)(h+2))
    int h = 0, rr2 = 0;
    #pragma unroll
    for (int hh = 0; hh < 8; ++hh) {
        int lo = 8 * hh * (hh + 1);
        if (rem >= lo) { h = hh; rr2 = rem - lo; }
    }
    int r = rr2 / (h + 1);
    int ci = rr2 - r * (h + 1);
    int qt = 16 * h + r;
    int nt = (qt >> 2) + 1;
    int kt0 = ci * 4;
    int kt1 = min(nt, kt0 + 4);
    int lastkt = qt >> 2;
    int q0 = qt * 16;

    const short* qrow = qm + (size_t)(b * TSEQ + q0 + col) * 64 + g * 8;
    bf16x8 qa0 = *(const bf16x8*)(qrow);
    bf16x8 qa1 = *(const bf16x8*)(qrow + 32);

    const short* kb_ = kq + (size_t)(b * 8 + g) * TSEQ * 8;
    const short* kb4 = kq + (size_t)(b * 8 + 4 + g) * TSEQ * 8;
    const short* vb_ = vq + ((size_t)b * 256 + g) * 64 * 8;

    float psum[4] = {0.f, 0.f, 0.f, 0.f};
    f32x4 o[4];
    #pragma unroll
    for (int df = 0; df < 4; ++df) o[df] = (f32x4){0.f, 0.f, 0.f, 0.f};

    short* Pw = &Pb[w][0];

    bf16x8 kcur[8], knxt[8];
    {
        int key0 = kt0 * 64 + col;
        #pragma unroll
        for (int kf = 0; kf < 4; ++kf) {
            kcur[kf * 2]     = *(const bf16x8*)(kb_ + (size_t)(key0 + kf * 16) * 8);
            kcur[kf * 2 + 1] = *(const bf16x8*)(kb4 + (size_t)(key0 + kf * 16) * 8);
        }
    }

    for (int kt = kt0; kt < kt1; ++kt) {
        int k0 = kt * 64;
        f32x4 s[4];
        #pragma unroll
        for (int kf = 0; kf < 4; ++kf) {
            f32x4 a = (f32x4){0.f, 0.f, 0.f, 0.f};
            a = mfma16(qa0, kcur[kf * 2], a);
            a = mfma16(qa1, kcur[kf * 2 + 1], a);
            s[kf] = a;
        }
        bf16x8 vfr[8];
        const short* vt0 = vb_ + (size_t)(k0 >> 3) * 64 * 8;
        #pragma unroll
        for (int df = 0; df < 4; ++df) {
            int d = df * 16 + col;
            vfr[df * 2]     = *(const bf16x8*)(vt0 + (size_t)d * 8);
            vfr[df * 2 + 1] = *(const bf16x8*)(vt0 + (size_t)(256 + d) * 8);
        }
        if (kt + 1 < kt1) {
            int key0 = (kt + 1) * 64 + col;
            #pragma unroll
            for (int kf = 0; kf < 4; ++kf) {
                knxt[kf * 2]     = *(const bf16x8*)(kb_ + (size_t)(key0 + kf * 16) * 8);
                knxt[kf * 2 + 1] = *(const bf16x8*)(kb4 + (size_t)(key0 + kf * 16) * 8);
            }
        }
        if (kt == lastkt) {
            #pragma unroll
            for (int kf = 0; kf < 4; ++kf) {
                int key = k0 + kf * 16 + col;
                #pragma unroll
                for (int j = 0; j < 4; ++j)
                    if (key > q0 + g * 4 + j) s[kf][j] = -1e30f;
            }
        }
        #pragma unroll
        for (int kf = 0; kf < 4; ++kf)
            #pragma unroll
            for (int j = 0; j < 4; ++j) {
                float pv = __expf(s[kf][j]);
                psum[j] += pv;
                int rr = g * 4 + j;
                int c = kf * 16 + col;
                Pw[rr * 64 + ((((c >> 3) ^ (rr & 7)) << 3) | (c & 7))] = f2bf(pv);
            }
        bf16x8 pa0 = *(const bf16x8*)(Pw + col * 64 + ((g ^ (col & 7)) << 3));
        bf16x8 pa1 = *(const bf16x8*)(Pw + col * 64 + (((4 + g) ^ (col & 7)) << 3));
        #pragma unroll
        for (int df = 0; df < 4; ++df) {
            o[df] = mfma16(pa0, vfr[df * 2], o[df]);
            o[df] = mfma16(pa1, vfr[df * 2 + 1], o[df]);
        }
        #pragma unroll
        for (int i2 = 0; i2 < 8; ++i2) kcur[i2] = knxt[i2];
    }

    // row-sum reduce across the 16 col lanes
    #pragma unroll
    for (int off = 1; off <= 8; off <<= 1)
        #pragma unroll
        for (int j = 0; j < 4; ++j)
            psum[j] += __shfl_xor(psum[j], off);

    // write partial slot (slot index == gid)
    #pragma unroll
    for (int df = 0; df < 4; ++df)
        #pragma unroll
        for (int j = 0; j < 4; ++j)
            pob[(size_t)gid * 1024 + (g * 4 + j) * 64 + df * 16 + col] = o[df][j];
    if (col == 0)
        #pragma unroll
        for (int j = 0; j < 4; ++j)
            pps[gid * 16 + g * 4 + j] = psum[j];
}

// Kernel 3: merge partials. grid 1024 x 256; 16 rows/block, 16 threads/row (float4).
__global__ __launch_bounds__(256) void merge_out(const float* __restrict__ pob,
                                                 const float* __restrict__ pps,
                                                 float* __restrict__ out) {
    int tid = threadIdx.x;
    int r = tid >> 4;
    int dq = tid & 15;
    int qr = blockIdx.x * 16 + r;       // global row 0..16383
    int b = qr >> 11;
    int t = qr & 2047;
    int qt = t >> 4, r16 = t & 15;
    int h = qt >> 4, rr = qt & 15;
    int slot0 = b * 576 + 8 * h * (h + 1) + rr * (h + 1);
    int nch = h + 1;
    float4 acc = {0.f, 0.f, 0.f, 0.f};
    float ps = 0.f;
    for (int ci = 0; ci < nch; ++ci) {
        const float* pb = pob + ((size_t)(slot0 + ci) * 16 + r16) * 64 + dq * 4;
        float4 v = *(const float4*)pb;
        acc.x += v.x; acc.y += v.y; acc.z += v.z; acc.w += v.w;
        ps += pps[(slot0 + ci) * 16 + r16];
    }
    float inv = 1.f / ps;
    float4 res = {acc.x * inv, acc.y * inv, acc.z * inv, acc.w * inv};
    *(float4*)&out[(size_t)qr * 64 + dq * 4] = res;
}

extern "C" void kernel_launch(void* const* d_in, const int* in_sizes, int n_in,
                              void* d_out, int out_size, void* d_ws, size_t ws_size,
                              hipStream_t stream) {
    const float* x  = (const float*)d_in[0];
    const float* Wq = (const float*)d_in[1];
    const float* Wk = (const float*)d_in[2];
    const float* Wv = (const float*)d_in[3];
    float* out = (float*)d_out;

    char* ws = (char*)d_ws;
    short* wt2 = (short*)(ws);                        // 384 KB
    short* qb  = (short*)(ws + 0x60000);              // 2 MB
    short* kqb = (short*)(ws + 0x260000);             // 2 MB
    short* vqb = (short*)(ws + 0x460000);             // 2 MB
    float* pps = (float*)(ws + 0x660000);             // 4608*16*4 = 288 KB
    float* pob = (float*)(ws + 0x700000);             // 4608*1024*4 = 18 MB

    prep_wt<<<128, 192, 0, stream>>>(Wq, Wk, Wv, wt2);
    qkv_gemm<<<512, 256, 0, stream>>>(x, wt2, qb, kqb, vqb);
    attn<<<1152, 256, 0, stream>>>(qb, kqb, vqb, pob, pps);
    merge_out<<<1024, 256, 0, stream>>>(pob, pps, out);
}

// Round 13
// 44.988 us; speedup vs baseline: 2.3395x; 1.0562x over previous
//
#include <hip/hip_runtime.h>
#include <hip/hip_bf16.h>
#include <stdint.h>

#define BATCH 8
#define TSEQ 2048
#define DM 1024
#define NQKV 192

typedef short bf16x8 __attribute__((ext_vector_type(8)));
typedef short short4v __attribute__((ext_vector_type(4)));
typedef float f32x4 __attribute__((ext_vector_type(4)));

static __device__ __forceinline__ short f2bf(float f) {
    union { float f; uint32_t u; } v; v.f = f;
    uint32_t u = v.u;
    uint32_t r = (u + 0x7FFFu + ((u >> 16) & 1u)) >> 16;
    return (short)r;
}

static __device__ __forceinline__ f32x4 mfma16(bf16x8 a, bf16x8 b, f32x4 c) {
    return __builtin_amdgcn_mfma_f32_16x16x32_bf16(a, b, c, 0, 0, 0);
}

static __device__ __forceinline__ int cvt_pk_bf16(float lo, float hi) {
    int r;
    asm("v_cvt_pk_bf16_f32 %0, %1, %2" : "=v"(r) : "v"(lo), "v"(hi));
    return r;
}

// Kernel 0: wt2[kchunk=0..127][n=0..191][8]. grid 128 x 192 threads.
__global__ __launch_bounds__(192) void prep_wt(const float* __restrict__ Wq,
                                               const float* __restrict__ Wk,
                                               const float* __restrict__ Wv,
                                               short* __restrict__ wt2) {
    int kc = blockIdx.x;
    int n = threadIdx.x;
    const float* src = (n < 64) ? Wq : (n < 128) ? Wk : Wv;
    int nn = n & 63;
    bf16x8 v;
    #pragma unroll
    for (int e = 0; e < 8; ++e)
        v[e] = f2bf(src[(kc * 8 + e) * 64 + nn]);
    *(bf16x8*)(wt2 + ((size_t)kc * 192 + n) * 8) = v;
}

// Kernel 1: QKV GEMM (R7 configuration, measured 15.1 us). Unchanged.
__global__ __launch_bounds__(256, 2) void qkv_gemm(const float* __restrict__ x,
                                                   const short* __restrict__ wt2,
                                                   short* __restrict__ qo,
                                                   short* __restrict__ kq,
                                                   short* __restrict__ vq) {
    __shared__ short Ab[2][32 * 32];
    __shared__ short Cs[32][192];
    int tid = threadIdx.x;
    int l = tid & 63, w = tid >> 6;
    int col = l & 15, g = l >> 4;
    int row0 = blockIdx.x * 32;

    int arow = tid >> 3, ap = tid & 7;
    const float* gA = x + (size_t)(row0 + arow) * DM + ap * 4;
    int awdst = arow * 32 + (((ap >> 1) ^ ((arow >> 1) & 3)) * 8) + (ap & 1) * 4;

    f32x4 acc[2][3];
    #pragma unroll
    for (int mf = 0; mf < 2; ++mf)
        #pragma unroll
        for (int nf = 0; nf < 3; ++nf) acc[mf][nf] = (f32x4){0.f, 0.f, 0.f, 0.f};

    float4 r0 = *(const float4*)(gA);
    float4 rcur = *(const float4*)(gA + 32);
    {
        short4v s = {f2bf(r0.x), f2bf(r0.y), f2bf(r0.z), f2bf(r0.w)};
        *(short4v*)&Ab[0][awdst] = s;
    }
    const short* bpw = wt2 + ((size_t)g * 192 + w * 48 + col) * 8;
    bf16x8 bcur[3], bnxt[3];
    #pragma unroll
    for (int nf = 0; nf < 3; ++nf)
        bcur[nf] = *(const bf16x8*)(bpw + (size_t)nf * 16 * 8);
    __syncthreads();

    int afr0, afr1;
    {
        int r0_ = col, r1_ = 16 + col;
        afr0 = r0_ * 32 + ((g ^ ((r0_ >> 1) & 3)) * 8);
        afr1 = r1_ * 32 + ((g ^ ((r1_ >> 1) & 3)) * 8);
    }

    for (int t = 0; t < 32; ++t) {
        float4 rn;
        if (t + 2 < 32) rn = *(const float4*)(gA + (t + 2) * 32);
        if (t + 1 < 32) {
            #pragma unroll
            for (int nf = 0; nf < 3; ++nf)
                bnxt[nf] = *(const bf16x8*)(bpw + ((size_t)(t + 1) * 4 * 192 + nf * 16) * 8);
            short4v s = {f2bf(rcur.x), f2bf(rcur.y), f2bf(rcur.z), f2bf(rcur.w)};
            *(short4v*)&Ab[(t + 1) & 1][awdst] = s;
        }
        bf16x8 a0 = *(const bf16x8*)&Ab[t & 1][afr0];
        bf16x8 a1 = *(const bf16x8*)&Ab[t & 1][afr1];
        #pragma unroll
        for (int nf = 0; nf < 3; ++nf) {
            acc[0][nf] = mfma16(a0, bcur[nf], acc[0][nf]);
            acc[1][nf] = mfma16(a1, bcur[nf], acc[1][nf]);
        }
        __syncthreads();
        rcur = rn;
        #pragma unroll
        for (int nf = 0; nf < 3; ++nf) bcur[nf] = bnxt[nf];
    }

    #pragma unroll
    for (int mf = 0; mf < 2; ++mf)
        #pragma unroll
        for (int nf = 0; nf < 3; ++nf) {
            int c = w * 48 + nf * 16 + col;
            #pragma unroll
            for (int j = 0; j < 4; ++j) {
                float sv = acc[mf][nf][j];
                if (c < 64) sv *= 0.03125f;
                Cs[mf * 16 + g * 4 + j][c] = f2bf(sv);
            }
        }
    __syncthreads();
    int b_ = row0 >> 11;
    int t0 = row0 & 2047;
    {
        int r = tid >> 3, c0 = (tid & 7) * 8;
        bf16x8 vv = *(const bf16x8*)&Cs[r][c0];
        *(bf16x8*)(qo + ((size_t)(b_ * TSEQ + t0 + r)) * 64 + c0) = vv;
    }
    {
        int chunk = tid >> 5, tl = tid & 31;
        bf16x8 vv = *(const bf16x8*)&Cs[tl][64 + chunk * 8];
        *(bf16x8*)(kq + ((size_t)(b_ * 8 + chunk) * TSEQ + t0 + tl) * 8) = vv;
    }
    {
        int tc = tid >> 6, d = tid & 63;
        bf16x8 vv;
        #pragma unroll
        for (int e = 0; e < 8; ++e) vv[e] = Cs[tc * 8 + e][128 + d];
        *(bf16x8*)(vq + (((size_t)b_ * 256 + (t0 >> 3) + tc) * 64 + d) * 8) = vv;
    }
}

// Kernel 2: causal flash attention — swapped QK^T, in-register P path.
// grid 384 x 256 (4 independent waves). Same work split as R6/R7.
// S^T = mfma(K,Q) puts P for q-row=col in registers; P->bf16 via cvt_pk;
// PV A-frags assembled with ds_bpermute (no P LDS round trip).
__global__ __launch_bounds__(256) void attn(const short* __restrict__ qm,
                                            const short* __restrict__ kq,
                                            const short* __restrict__ vq,
                                            float* __restrict__ out) {
    __shared__ float Om[2][16][64];
    __shared__ float Ps[2][16];
    int tid = threadIdx.x;
    int l = tid & 63, w = tid >> 6;
    int col = l & 15, g = l >> 4;

    int Bk = blockIdx.x;
    int bb = Bk & 7;
    int jj = Bk >> 3;
    bool high = (jj < 32);
    int qt, kt0, kt1;
    if (high) {
        int hp = 62 - 2 * jj + (w >> 1);
        qt = 64 + hp;
        int nt = (qt >> 2) + 1;
        int nh = nt >> 1;
        kt0 = (w & 1) ? nh : 0;
        kt1 = (w & 1) ? nt : nh;
    } else {
        int i = 47 - jj;
        qt = 4 * i + w;
        kt0 = 0;
        kt1 = (qt >> 2) + 1;
    }
    int q0 = qt * 16;
    int lastkt = qt >> 2;

    const short* qrow = qm + (size_t)(bb * TSEQ + q0 + col) * 64 + g * 8;
    bf16x8 qa0 = *(const bf16x8*)(qrow);
    bf16x8 qa1 = *(const bf16x8*)(qrow + 32);

    const short* kb_ = kq + (size_t)(bb * 8 + g) * TSEQ * 8;
    const short* kb4 = kq + (size_t)(bb * 8 + 4 + g) * TSEQ * 8;
    const short* vb_ = vq + ((size_t)bb * 256 + g) * 64 * 8;

    float psum = 0.f;
    f32x4 o[4];
    #pragma unroll
    for (int df = 0; df < 4; ++df) o[df] = (f32x4){0.f, 0.f, 0.f, 0.f};

    // bpermute addresses (bytes): source lane = col + 16*(2*(g&1)+(m>>1))
    int addr0 = (col + ((g & 1) << 5)) * 4;
    int addr1 = addr0 + 64;
    bool ghi = (g >> 1) != 0;

    bf16x8 kcur[8], knxt[8];
    {
        int key0 = kt0 * 64 + col;
        #pragma unroll
        for (int kf = 0; kf < 4; ++kf) {
            kcur[kf * 2]     = *(const bf16x8*)(kb_ + (size_t)(key0 + kf * 16) * 8);
            kcur[kf * 2 + 1] = *(const bf16x8*)(kb4 + (size_t)(key0 + kf * 16) * 8);
        }
    }

    for (int kt = kt0; kt < kt1; ++kt) {
        int k0 = kt * 64;
        // S^T = K Q^T : lane holds S[q=col][key=k0+kf*16+g*4+j] in st[kf][j]
        f32x4 st[4];
        #pragma unroll
        for (int kf = 0; kf < 4; ++kf) {
            f32x4 a = (f32x4){0.f, 0.f, 0.f, 0.f};
            a = mfma16(kcur[kf * 2], qa0, a);
            a = mfma16(kcur[kf * 2 + 1], qa1, a);
            st[kf] = a;
        }
        // V fragments (current tile)
        bf16x8 vfr[8];
        const short* vt0 = vb_ + (size_t)(k0 >> 3) * 64 * 8;
        #pragma unroll
        for (int df = 0; df < 4; ++df) {
            int d = df * 16 + col;
            vfr[df * 2]     = *(const bf16x8*)(vt0 + (size_t)d * 8);
            vfr[df * 2 + 1] = *(const bf16x8*)(vt0 + (size_t)(256 + d) * 8);
        }
        // K prefetch (next tile)
        if (kt + 1 < kt1) {
            int key0 = (kt + 1) * 64 + col;
            #pragma unroll
            for (int kf = 0; kf < 4; ++kf) {
                knxt[kf * 2]     = *(const bf16x8*)(kb_ + (size_t)(key0 + kf * 16) * 8);
                knxt[kf * 2 + 1] = *(const bf16x8*)(kb4 + (size_t)(key0 + kf * 16) * 8);
            }
        }
        // mask (diagonal tile): key > q
        if (kt == lastkt) {
            #pragma unroll
            for (int kf = 0; kf < 4; ++kf) {
                #pragma unroll
                for (int j = 0; j < 4; ++j)
                    if (k0 + kf * 16 + g * 4 + j > q0 + col) st[kf][j] = -1e30f;
            }
        }
        // p = exp(s), per-lane partial row sum, pack to bf16 pairs
        int pk[4][2];
        #pragma unroll
        for (int kf = 0; kf < 4; ++kf) {
            float p0 = __expf(st[kf][0]);
            float p1 = __expf(st[kf][1]);
            float p2 = __expf(st[kf][2]);
            float p3 = __expf(st[kf][3]);
            psum += (p0 + p1) + (p2 + p3);
            pk[kf][0] = cvt_pk_bf16(p0, p1);
            pk[kf][1] = cvt_pk_bf16(p2, p3);
        }
        // assemble PV A-fragments via bpermute:
        // word m of (col,g) = pair (m&1) of kf=2ks+(g>=2) from lane col+16*(2(g&1)+(m>>1))
        #pragma unroll
        for (int ks = 0; ks < 2; ++ks) {
            union { int i[4]; bf16x8 v; } A;
            int rA, rB;
            rA = __builtin_amdgcn_ds_bpermute(addr0, pk[2 * ks][0]);
            rB = __builtin_amdgcn_ds_bpermute(addr0, pk[2 * ks + 1][0]);
            A.i[0] = ghi ? rB : rA;
            rA = __builtin_amdgcn_ds_bpermute(addr0, pk[2 * ks][1]);
            rB = __builtin_amdgcn_ds_bpermute(addr0, pk[2 * ks + 1][1]);
            A.i[1] = ghi ? rB : rA;
            rA = __builtin_amdgcn_ds_bpermute(addr1, pk[2 * ks][0]);
            rB = __builtin_amdgcn_ds_bpermute(addr1, pk[2 * ks + 1][0]);
            A.i[2] = ghi ? rB : rA;
            rA = __builtin_amdgcn_ds_bpermute(addr1, pk[2 * ks][1]);
            rB = __builtin_amdgcn_ds_bpermute(addr1, pk[2 * ks + 1][1]);
            A.i[3] = ghi ? rB : rA;
            #pragma unroll
            for (int df = 0; df < 4; ++df)
                o[df] = mfma16(A.v, vfr[df * 2 + ks], o[df]);
        }
        #pragma unroll
        for (int i2 = 0; i2 < 8; ++i2) kcur[i2] = knxt[i2];
    }

    // full row sums: reduce partials across the 4 g-groups (q = col)
    psum += __shfl_xor(psum, 16);
    psum += __shfl_xor(psum, 32);
    // fetch psum for q = g*4+j (output rows live at q=(g*4+j), d=col layout)
    float psj[4];
    #pragma unroll
    for (int j = 0; j < 4; ++j) psj[j] = __shfl(psum, g * 4 + j);

    if (high) {
        int pr = w >> 1;
        if (w & 1) {
            #pragma unroll
            for (int df = 0; df < 4; ++df)
                #pragma unroll
                for (int j = 0; j < 4; ++j)
                    Om[pr][g * 4 + j][df * 16 + col] = o[df][j];
            if (col == 0)
                #pragma unroll
                for (int j = 0; j < 4; ++j) Ps[pr][g * 4 + j] = psj[j];
        }
        __syncthreads();
        if (!(w & 1)) {
            float inv[4];
            #pragma unroll
            for (int j = 0; j < 4; ++j) inv[j] = 1.f / (psj[j] + Ps[pr][g * 4 + j]);
            #pragma unroll
            for (int df = 0; df < 4; ++df)
                #pragma unroll
                for (int j = 0; j < 4; ++j) {
                    float vv = (o[df][j] + Om[pr][g * 4 + j][df * 16 + col]) * inv[j];
                    out[(size_t)(bb * TSEQ + q0 + g * 4 + j) * 64 + df * 16 + col] = vv;
                }
        }
    } else {
        #pragma unroll
        for (int df = 0; df < 4; ++df)
            #pragma unroll
            for (int j = 0; j < 4; ++j)
                out[(size_t)(bb * TSEQ + q0 + g * 4 + j) * 64 + df * 16 + col] = o[df][j] / psj[j];
    }
}

extern "C" void kernel_launch(void* const* d_in, const int* in_sizes, int n_in,
                              void* d_out, int out_size, void* d_ws, size_t ws_size,
                              hipStream_t stream) {
    const float* x  = (const float*)d_in[0];
    const float* Wq = (const float*)d_in[1];
    const float* Wk = (const float*)d_in[2];
    const float* Wv = (const float*)d_in[3];
    float* out = (float*)d_out;

    char* ws = (char*)d_ws;
    short* wt2 = (short*)(ws);                        // 384 KB
    short* qb  = (short*)(ws + 0x60000);              // 2 MB
    short* kqb = (short*)(ws + 0x260000);             // 2 MB
    short* vqb = (short*)(ws + 0x460000);             // 2 MB

    prep_wt<<<128, 192, 0, stream>>>(Wq, Wk, Wv, wt2);
    qkv_gemm<<<512, 256, 0, stream>>>(x, wt2, qb, kqb, vqb);
    attn<<<384, 256, 0, stream>>>(qb, kqb, vqb, out);
}